// Round 13
// baseline (161.917 us; speedup 1.0000x reference)
//
#include <hip/hip_runtime.h>

// Problem constants: C=1024, RC=64, L=49 (7x7), LQ=64 (8x8), BZ=4, N=256, BP=1024

typedef float v4f __attribute__((ext_vector_type(4)));

// ---- workspace layout (float offsets) ----
#define WQBAR  0         // [4][49] qbar (mean over s of q_feat), includes 1/64
#define WPCBW  320       // [1024] mean over r of pc_w rows (includes 1/64)
#define WPCBB  1344      // [1] mean of pc_b
#define WQF    1408      // [4][64][49] q_feat
#define WPMBF  14336     // bf16 [64][1024] pm_w transposed (as 32768 floats)
#define WQMBF  47104     // bf16 [64][1024] qm_w transposed

// ---- output layout (float offsets) ----
#define OUT_FP 0          // f_props [1024][1024][49]
#define OUT_FQ 51380224   // f_query [1024][1024][64]
#define OUT_PA 118489088  // p_att   [1024][1024]

__device__ __forceinline__ float sigmoidf(float v) {
    return 1.0f / (1.0f + __expf(-v));
}
__device__ __forceinline__ unsigned short bf16_rne(float x) {
    unsigned u = __float_as_uint(x);
    return (unsigned short)((u + 0x7FFFu + ((u >> 16) & 1u)) >> 16);
}
// exact floor(e/49) for e < ~5e9 (M=ceil(2^37/49), M*49-2^37=26)
__device__ __forceinline__ unsigned div49(unsigned e) {
    return __umulhi(e, 2804876602u) >> 5;
}

// K1: one launch for all prep.
__global__ __launch_bounds__(1024) void k_prepall(
    const float* __restrict__ xq, const float* __restrict__ qc_w,
    const float* __restrict__ qc_b, const float* __restrict__ pc_w,
    const float* __restrict__ pc_b, const float* __restrict__ pm_w,
    const float* __restrict__ qm_w, float* __restrict__ ws)
{
    const int blk = blockIdx.x, t = threadIdx.x;
    if (blk < 196) {
        __shared__ float rq[1024];
        __shared__ float qf_s[64];
        const int b = blk / 49, l = blk - b * 49;
        const int wave = t >> 6, lane = t & 63;
        const int i = l / 7, j = l - i * 7;
        float fi = (2 * i + 1) * (1.0f / 14.0f);
        float fj = (2 * j + 1) * (1.0f / 14.0f);
        float wi0 = (1.0f - 0.875f * fi) * (1.0f / 1.125f); float wi1 = 1.0f - wi0;
        float wj0 = (1.0f - 0.875f * fj) * (1.0f / 1.125f); float wj1 = 1.0f - wj0;
        const float* X = xq + ((size_t)(b * 1024 + t) << 6);
        rq[t] = wi0 * (wj0 * X[i * 8 + j]       + wj1 * X[i * 8 + j + 1])
              + wi1 * (wj0 * X[(i + 1) * 8 + j] + wj1 * X[(i + 1) * 8 + j + 1]);
        __syncthreads();
        #pragma unroll
        for (int ii = 0; ii < 4; ++ii) {
            int s = wave * 4 + ii;
            const float* wr = qc_w + s * 1024;
            float part = 0.0f;
            #pragma unroll
            for (int k = 0; k < 16; ++k) part += wr[k * 64 + lane] * rq[k * 64 + lane];
            #pragma unroll
            for (int off = 32; off; off >>= 1) part += __shfl_down(part, off, 64);
            if (lane == 0) {
                float val = part + qc_b[s];
                ws[WQF + b * 3136 + s * 49 + l] = val;
                qf_s[s] = val;
            }
        }
        __syncthreads();
        if (t == 0) {
            float s = 0.0f;
            #pragma unroll
            for (int k = 0; k < 64; ++k) s += qf_s[k];
            ws[WQBAR + b * 49 + l] = s * (1.0f / 64.0f);
        }
    } else if (blk == 196) {
        float s = 0.0f;
        for (int r = 0; r < 64; ++r) s += pc_w[r * 1024 + t];
        ws[WPCBW + t] = s * (1.0f / 64.0f);
        if (t == 0) {
            float sb = 0.0f;
            for (int r = 0; r < 64; ++r) sb += pc_b[r];
            ws[WPCBB] = sb * (1.0f / 64.0f);
        }
    } else {
        int idx = (blk - 197) * 1024 + t;  // < 131072
        int r = (idx & 65535) >> 10, c = idx & 1023;
        float w = (idx < 65536) ? pm_w[c * 64 + r] : qm_w[c * 64 + r];
        unsigned short* dst = (unsigned short*)(ws + (idx < 65536 ? WPMBF : WQMBF));
        dst[idx & 65535] = bf16_rne(w);
    }
}

// K2: fully fused per-prop kernel, 512 threads, 100% occupancy target:
// 1024 blocks x 8 waves = 32 waves/CU (4 blocks/CU x 2048 threads).
// __launch_bounds__(512,8) caps VGPR at 64 so the full 32 waves fit.
// Phase 1: 8 chunks of [128][49], single-buffered LDS staging.
// Phase 2: p_rel/q_rel + bf16 MLPs -> p_att (y_s + global), q_att (pcb_s).
// Phase 3: f_props (x re-read L3-hot, NT stores, division-free indexing).
// Phase 4: f_query (x_query L2-hot, NT stores).
__global__ __launch_bounds__(512, 8) void k_main(
    const float* __restrict__ x, const float* __restrict__ xq,
    const float* __restrict__ pc_w, const float* __restrict__ pc_b,
    const float* __restrict__ pm_b, const float* __restrict__ qm_b,
    float* __restrict__ ws, float* __restrict__ patt_out,
    float* __restrict__ fprops, float* __restrict__ fquery)
{
    __shared__ float xs[6272];        // [128][49] one channel-chunk (24.5 KB)
    __shared__ float y_s[1024];       // y; reused as p_att
    __shared__ float pcb_s[1024];     // pc row-means; reused as q_att
    __shared__ float qbar_s[49];
    __shared__ float sq_s;
    __shared__ float pbar_part[6][49];
    __shared__ float pbar_s[49];
    __shared__ float prel_s[64];
    __shared__ float qrel_s[64];

    const int t = threadIdx.x, wave = t >> 6, lane = t & 63;
    const int p = blockIdx.x, b = p >> 8;

    if (t < 49) qbar_s[t] = ws[WQBAR + b * 49 + t];
    for (int k = t; k < 1024; k += 512) pcb_s[k] = ws[WPCBW + k];
    const float pcbarb = ws[WPCBB];

    const float4* xp4 = (const float4*)(x + (size_t)p * 50176);

    // pbar split for waves 2..7 over 128 channels: counts {22,21,21,22,21,21}
    const int w6 = wave - 2;
    const int poff = 21 * w6 + (w6 >= 1) + (w6 >= 4);
    const int pcnt = 21 + (w6 == 0) + (w6 == 3);
    float pbar_acc = 0.0f;

    for (int ch = 0; ch < 8; ++ch) {
        __syncthreads();                       // xs free of prev readers (iter0: covers init)
        const float4* src = xp4 + ch * 1568;
        float4* xs4 = (float4*)xs;
        for (int k = t; k < 1568; k += 512) xs4[k] = src[k];
        __syncthreads();
        if (ch == 0 && t == 0) {               // sumqbar, once (qbar_s visible)
            float s = 0.0f;
            #pragma unroll
            for (int l = 0; l < 49; ++l) s += qbar_s[l];
            sq_s = s;
        }
        if (wave < 2) {
            int c = wave * 64 + lane;          // 0..127 within chunk
            const float* row = xs + c * 49;
            float acc = 0.0f;
            #pragma unroll
            for (int l = 0; l < 49; ++l) acc += row[l] * qbar_s[l];
            y_s[ch * 128 + c] = acc;
        } else if (lane < 49) {
            const float* base = xs + poff * 49 + lane;
            const float* pw = pcb_s + ch * 128 + poff;
            float a = 0.0f;
            for (int c = 0; c < pcnt; ++c) a += pw[c] * base[c * 49];
            pbar_acc += a;
        }
    }
    if (wave >= 2 && lane < 49) pbar_part[wave - 2][lane] = pbar_acc;
    __syncthreads();
    if (t < 49) {
        float s = pcbarb;
        #pragma unroll
        for (int w = 0; w < 6; ++w) s += pbar_part[w][t];
        pbar_s[t] = s;
    }
    __syncthreads();
    const float sumqbar = sq_s;

    // p_rel[r] = pc_w[r,:].y + pc_b[r]*sumqbar ; 8 waves x 8 rows
    #pragma unroll
    for (int i = 0; i < 8; ++i) {
        int r = wave * 8 + i;
        const float* wr = pc_w + r * 1024;
        float part = 0.0f;
        #pragma unroll
        for (int k = 0; k < 16; ++k) part += wr[k * 64 + lane] * y_s[k * 64 + lane];
        #pragma unroll
        for (int off = 32; off; off >>= 1) part += __shfl_down(part, off, 64);
        if (lane == 0) prel_s[r] = part + pc_b[r] * sumqbar;
    }
    if (t < 64) {
        const float* qfr = ws + WQF + (b * 3136 + t * 49);
        float a = 0.0f;
        #pragma unroll
        for (int l = 0; l < 49; ++l) a += pbar_s[l] * qfr[l];
        qrel_s[t] = a;
    }
    __syncthreads();

    // MLPs (bf16 weights): thread t -> p cols {2t,2t+1} and q cols {2t,2t+1}
    {
        const unsigned* wp = (const unsigned*)(ws + WPMBF);
        const unsigned* wq = (const unsigned*)(ws + WQMBF);
        float ap0 = 0.0f, ap1 = 0.0f, aq0 = 0.0f, aq1 = 0.0f;
        #pragma unroll 16
        for (int r = 0; r < 64; ++r) {
            float pr = prel_s[r], qr = qrel_s[r];
            unsigned pw2 = wp[r * 512 + t];
            unsigned qw2 = wq[r * 512 + t];
            ap0 += __uint_as_float(pw2 << 16) * pr;
            ap1 += __uint_as_float(pw2 & 0xFFFF0000u) * pr;
            aq0 += __uint_as_float(qw2 << 16) * qr;
            aq1 += __uint_as_float(qw2 & 0xFFFF0000u) * qr;
        }
        float2 pb = ((const float2*)pm_b)[t];
        float2 qb = ((const float2*)qm_b)[t];
        float2 po, qo;
        po.x = sigmoidf(ap0 + pb.x); po.y = sigmoidf(ap1 + pb.y);
        qo.x = sigmoidf(aq0 + qb.x); qo.y = sigmoidf(aq1 + qb.y);
        ((float2*)patt_out)[p * 512 + t] = po;
        ((float2*)y_s)[t]   = po;              // p_att (y_s readers done)
        ((float2*)pcb_s)[t] = qo;              // q_att
    }
    __syncthreads();

    // Phase 3: f_props = x * p_att. Division-free channel tracking:
    // per iter e += 2048 = 49*41 + 39.
    {
        const v4f* xg4 = (const v4f*)(x + (size_t)p * 50176);
        v4f* fp4 = (v4f*)(fprops + (size_t)p * 50176);
        unsigned e0 = 4u * (unsigned)t;
        unsigned c0 = div49(e0);
        unsigned m = e0 - 49u * c0;
        for (int k = t; k < 12544; k += 512) {
            float a0 = y_s[c0];
            float a1 = y_s[c0 + (m >= 46u)];
            v4f v = xg4[k];
            v4f g;
            g.x = a0;
            g.y = (m >= 48u) ? a1 : a0;
            g.z = (m >= 47u) ? a1 : a0;
            g.w = (m >= 46u) ? a1 : a0;
            __builtin_nontemporal_store(v * g, fp4 + k);
            c0 += 41u; m += 39u;
            if (m >= 49u) { m -= 49u; ++c0; }
        }
    }

    // Phase 4: f_query = x_query[b] * q_att. 16384 float4 = 32 iters x 512.
    {
        const v4f* xq4 = (const v4f*)(xq + ((size_t)b << 16));
        v4f* fq4 = (v4f*)(fquery + ((size_t)p << 16));
        for (int k = t; k < 16384; k += 512) {
            float att = pcb_s[k >> 4];
            v4f v = xq4[k];
            __builtin_nontemporal_store(v * att, fq4 + k);
        }
    }
}

extern "C" void kernel_launch(void* const* d_in, const int* in_sizes, int n_in,
                              void* d_out, int out_size, void* d_ws, size_t ws_size,
                              hipStream_t stream) {
    const float* x_props = (const float*)d_in[0];
    const float* x_query = (const float*)d_in[1];
    const float* pc_w    = (const float*)d_in[2];
    const float* pc_b    = (const float*)d_in[3];
    const float* qc_w    = (const float*)d_in[4];
    const float* qc_b    = (const float*)d_in[5];
    const float* pm_w    = (const float*)d_in[6];
    const float* pm_b    = (const float*)d_in[7];
    const float* qm_w    = (const float*)d_in[8];
    const float* qm_b    = (const float*)d_in[9];
    float* out = (float*)d_out;
    float* ws  = (float*)d_ws;

    k_prepall<<<325, 1024, 0, stream>>>(x_query, qc_w, qc_b, pc_w, pc_b, pm_w, qm_w, ws);
    k_main<<<1024, 512, 0, stream>>>(x_props, x_query, pc_w, pc_b, pm_b, qm_b, ws,
                                     out + OUT_PA, out + OUT_FP, out + OUT_FQ);
}

// Round 14
// 156.631 us; speedup vs baseline: 1.0338x; 1.0338x over previous
//
#include <hip/hip_runtime.h>

// Problem constants: C=1024, RC=64, L=49 (7x7), LQ=64 (8x8), BZ=4, N=256, BP=1024

typedef float v4f __attribute__((ext_vector_type(4)));

// ---- workspace layout (float offsets) ----
#define WQBAR  0         // [4][49] qbar (mean over s of q_feat), includes 1/64
#define WPCBW  320       // [1024] mean over r of pc_w rows (includes 1/64)
#define WPCBB  1344      // [1] mean of pc_b
#define WQF    1408      // [4][64][49] q_feat
#define WPMBF  14336     // bf16 [64][1024] pm_w transposed (as 32768 floats)
#define WQMBF  47104     // bf16 [64][1024] qm_w transposed

// ---- output layout (float offsets) ----
#define OUT_FP 0          // f_props [1024][1024][49]
#define OUT_FQ 51380224   // f_query [1024][1024][64]
#define OUT_PA 118489088  // p_att   [1024][1024]

__device__ __forceinline__ float sigmoidf(float v) {
    return 1.0f / (1.0f + __expf(-v));
}
__device__ __forceinline__ unsigned short bf16_rne(float x) {
    unsigned u = __float_as_uint(x);
    return (unsigned short)((u + 0x7FFFu + ((u >> 16) & 1u)) >> 16);
}
// exact floor(e/49) for e < ~5e9 (M=ceil(2^37/49), M*49-2^37=26)
__device__ __forceinline__ unsigned div49(unsigned e) {
    return __umulhi(e, 2804876602u) >> 5;
}

// K1: one launch for all prep.
__global__ __launch_bounds__(1024) void k_prepall(
    const float* __restrict__ xq, const float* __restrict__ qc_w,
    const float* __restrict__ qc_b, const float* __restrict__ pc_w,
    const float* __restrict__ pc_b, const float* __restrict__ pm_w,
    const float* __restrict__ qm_w, float* __restrict__ ws)
{
    const int blk = blockIdx.x, t = threadIdx.x;
    if (blk < 196) {
        __shared__ float rq[1024];
        __shared__ float qf_s[64];
        const int b = blk / 49, l = blk - b * 49;
        const int wave = t >> 6, lane = t & 63;
        const int i = l / 7, j = l - i * 7;
        float fi = (2 * i + 1) * (1.0f / 14.0f);
        float fj = (2 * j + 1) * (1.0f / 14.0f);
        float wi0 = (1.0f - 0.875f * fi) * (1.0f / 1.125f); float wi1 = 1.0f - wi0;
        float wj0 = (1.0f - 0.875f * fj) * (1.0f / 1.125f); float wj1 = 1.0f - wj0;
        const float* X = xq + ((size_t)(b * 1024 + t) << 6);
        rq[t] = wi0 * (wj0 * X[i * 8 + j]       + wj1 * X[i * 8 + j + 1])
              + wi1 * (wj0 * X[(i + 1) * 8 + j] + wj1 * X[(i + 1) * 8 + j + 1]);
        __syncthreads();
        #pragma unroll
        for (int ii = 0; ii < 4; ++ii) {
            int s = wave * 4 + ii;
            const float* wr = qc_w + s * 1024;
            float part = 0.0f;
            #pragma unroll
            for (int k = 0; k < 16; ++k) part += wr[k * 64 + lane] * rq[k * 64 + lane];
            #pragma unroll
            for (int off = 32; off; off >>= 1) part += __shfl_down(part, off, 64);
            if (lane == 0) {
                float val = part + qc_b[s];
                ws[WQF + b * 3136 + s * 49 + l] = val;
                qf_s[s] = val;
            }
        }
        __syncthreads();
        if (t == 0) {
            float s = 0.0f;
            #pragma unroll
            for (int k = 0; k < 64; ++k) s += qf_s[k];
            ws[WQBAR + b * 49 + l] = s * (1.0f / 64.0f);
        }
    } else if (blk == 196) {
        float s = 0.0f;
        for (int r = 0; r < 64; ++r) s += pc_w[r * 1024 + t];
        ws[WPCBW + t] = s * (1.0f / 64.0f);
        if (t == 0) {
            float sb = 0.0f;
            for (int r = 0; r < 64; ++r) sb += pc_b[r];
            ws[WPCBB] = sb * (1.0f / 64.0f);
        }
    } else {
        int idx = (blk - 197) * 1024 + t;  // < 131072
        int r = (idx & 65535) >> 10, c = idx & 1023;
        float w = (idx < 65536) ? pm_w[c * 64 + r] : qm_w[c * 64 + r];
        unsigned short* dst = (unsigned short*)(ws + (idx < 65536 ? WPMBF : WQMBF));
        dst[idx & 65535] = bf16_rne(w);
    }
}

// K2: fully fused per-prop kernel, software-pipelined staging (round-12 best).
__global__ __launch_bounds__(256) void k_main(
    const float* __restrict__ x, const float* __restrict__ xq,
    const float* __restrict__ pc_w, const float* __restrict__ pc_b,
    const float* __restrict__ pm_b, const float* __restrict__ qm_b,
    float* __restrict__ ws, float* __restrict__ patt_out,
    float* __restrict__ fprops, float* __restrict__ fquery)
{
    __shared__ float xs[6272];        // 2 x [64][49] chunk buffers (25 KB)
    __shared__ float y_s[1024];       // y; reused as p_att
    __shared__ float pcb_s[1024];     // pc row-means; reused as q_att
    __shared__ float qbar_s[49];
    __shared__ float sq_s;
    __shared__ float pbar_part[3][49];
    __shared__ float pbar_s[49];
    __shared__ float prel_s[64];
    __shared__ float qrel_s[64];

    const int t = threadIdx.x, wave = t >> 6, lane = t & 63;
    const int p = blockIdx.x, b = p >> 8;

    if (t < 49) qbar_s[t] = ws[WQBAR + b * 49 + t];
    for (int k = t; k < 1024; k += 256) pcb_s[k] = ws[WPCBW + k];
    const float pcbarb = ws[WPCBB];

    const float4* xp4 = (const float4*)(x + (size_t)p * 50176);
    float4* xs4 = (float4*)xs;

    // pbar work split for waves 1..3: channel ranges {0..21, 22..42, 43..63}
    const int poff = (wave == 1) ? 0 : (wave == 2) ? 22 : 43;
    const int pcnt = (wave == 1) ? 22 : 21;
    float pbar_acc = 0.0f;

    // prologue: chunk 0 -> buf 0
    {
        const float4* src = xp4;               // 784 float4
        float4 r0 = src[t], r1 = src[t + 256], r2 = src[t + 512];
        float4 r3;
        if (t < 16) r3 = src[t + 768];
        xs4[t] = r0; xs4[t + 256] = r1; xs4[t + 512] = r2;
        if (t < 16) xs4[t + 768] = r3;
    }
    __syncthreads();

    for (int g = 0; g < 16; ++g) {
        // issue next chunk's global loads (overlap with compute below)
        float4 r0, r1, r2, r3;
        if (g < 15) {
            const float4* src = xp4 + (g + 1) * 784;
            r0 = src[t]; r1 = src[t + 256]; r2 = src[t + 512];
            if (t < 16) r3 = src[t + 768];
        }
        if (g == 0 && t == 0) {                // sumqbar, once
            float s = 0.0f;
            #pragma unroll
            for (int l = 0; l < 49; ++l) s += qbar_s[l];
            sq_s = s;
        }
        // compute chunk g from buf (g&1)
        const float* xb = xs + (g & 1) * 3136;
        if (wave == 0) {
            const float* row = xb + lane * 49;
            float acc = 0.0f;
            #pragma unroll
            for (int l = 0; l < 49; ++l) acc += row[l] * qbar_s[l];
            y_s[g * 64 + lane] = acc;
        } else if (lane < 49) {
            const float* base = xb + poff * 49 + lane;
            const float* pw = pcb_s + g * 64 + poff;
            float a = 0.0f;
            for (int c = 0; c < pcnt; ++c) a += pw[c] * base[c * 49];
            pbar_acc += a;
        }
        // stage next chunk into the other buffer
        if (g < 15) {
            float* xw = xs + ((g + 1) & 1) * 3136;
            float4* xw4 = (float4*)xw;
            xw4[t] = r0; xw4[t + 256] = r1; xw4[t + 512] = r2;
            if (t < 16) xw4[t + 768] = r3;
        }
        __syncthreads();
    }
    if (wave >= 1 && lane < 49) pbar_part[wave - 1][lane] = pbar_acc;
    __syncthreads();
    if (t < 49) pbar_s[t] = pbar_part[0][t] + pbar_part[1][t] + pbar_part[2][t] + pcbarb;
    __syncthreads();
    const float sumqbar = sq_s;

    // p_rel[r] = pc_w[r,:].y + pc_b[r]*sumqbar ; 4 waves x 16 rows
    #pragma unroll
    for (int i = 0; i < 16; ++i) {
        int r = wave * 16 + i;
        const float* wr = pc_w + r * 1024;
        float part = 0.0f;
        #pragma unroll
        for (int k = 0; k < 16; ++k) part += wr[k * 64 + lane] * y_s[k * 64 + lane];
        #pragma unroll
        for (int off = 32; off; off >>= 1) part += __shfl_down(part, off, 64);
        if (lane == 0) prel_s[r] = part + pc_b[r] * sumqbar;
    }
    if (t < 64) {
        const float* qfr = ws + WQF + (b * 3136 + t * 49);
        float a = 0.0f;
        #pragma unroll
        for (int l = 0; l < 49; ++l) a += pbar_s[l] * qfr[l];
        qrel_s[t] = a;
    }
    __syncthreads();

    // MLPs (bf16 weights): each thread 4 p-cols + 4 q-cols.
    {
        const unsigned* wp = (const unsigned*)(ws + WPMBF);
        const unsigned* wq = (const unsigned*)(ws + WQMBF);
        float4 ap = {0, 0, 0, 0}, aq = {0, 0, 0, 0};
        #pragma unroll
        for (int r = 0; r < 64; ++r) {
            float pr = prel_s[r], qr = qrel_s[r];
            unsigned p01 = wp[r * 512 + 2 * t];
            unsigned p23 = wp[r * 512 + 2 * t + 1];
            ap.x += __uint_as_float(p01 << 16) * pr;
            ap.y += __uint_as_float(p01 & 0xFFFF0000u) * pr;
            ap.z += __uint_as_float(p23 << 16) * pr;
            ap.w += __uint_as_float(p23 & 0xFFFF0000u) * pr;
            unsigned q01 = wq[r * 512 + 2 * t];
            unsigned q23 = wq[r * 512 + 2 * t + 1];
            aq.x += __uint_as_float(q01 << 16) * qr;
            aq.y += __uint_as_float(q01 & 0xFFFF0000u) * qr;
            aq.z += __uint_as_float(q23 << 16) * qr;
            aq.w += __uint_as_float(q23 & 0xFFFF0000u) * qr;
        }
        float4 pb = ((const float4*)pm_b)[t];
        float4 qb = ((const float4*)qm_b)[t];
        float4 po, qo;
        po.x = sigmoidf(ap.x + pb.x); po.y = sigmoidf(ap.y + pb.y);
        po.z = sigmoidf(ap.z + pb.z); po.w = sigmoidf(ap.w + pb.w);
        qo.x = sigmoidf(aq.x + qb.x); qo.y = sigmoidf(aq.y + qb.y);
        qo.z = sigmoidf(aq.z + qb.z); qo.w = sigmoidf(aq.w + qb.w);
        ((float4*)patt_out)[p * 256 + t] = po;
        __syncthreads();                       // y_s readers (p_rel) done
        ((float4*)y_s)[t]   = po;              // p_att
        ((float4*)pcb_s)[t] = qo;              // q_att
    }
    __syncthreads();

    // Phase 3: f_props = x * p_att. Division-free channel tracking:
    // per iter e += 1024 = 49*20 + 44.
    {
        const v4f* xg4 = (const v4f*)(x + (size_t)p * 50176);
        v4f* fp4 = (v4f*)(fprops + (size_t)p * 50176);
        unsigned e0 = 4u * (unsigned)t;
        unsigned c0 = div49(e0);
        unsigned m = e0 - 49u * c0;
        for (int i = 0; i < 49; ++i) {
            int k = i * 256 + t;
            float a0 = y_s[c0];
            float a1 = y_s[c0 + (m >= 46u)];
            v4f v = xg4[k];
            v4f g;
            g.x = a0;
            g.y = (m >= 48u) ? a1 : a0;
            g.z = (m >= 47u) ? a1 : a0;
            g.w = (m >= 46u) ? a1 : a0;
            __builtin_nontemporal_store(v * g, fp4 + k);
            c0 += 20u; m += 44u;
            if (m >= 49u) { m -= 49u; ++c0; }
        }
    }

    // Phase 4: f_query = x_query[b] * q_att. 16384 float4 = 64 iters x 256.
    {
        const v4f* xq4 = (const v4f*)(xq + ((size_t)b << 16));
        v4f* fq4 = (v4f*)(fquery + ((size_t)p << 16));
        for (int i = 0; i < 64; ++i) {
            int k = i * 256 + t;
            float att = pcb_s[k >> 4];
            v4f v = xq4[k];
            __builtin_nontemporal_store(v * att, fq4 + k);
        }
    }
}

extern "C" void kernel_launch(void* const* d_in, const int* in_sizes, int n_in,
                              void* d_out, int out_size, void* d_ws, size_t ws_size,
                              hipStream_t stream) {
    const float* x_props = (const float*)d_in[0];
    const float* x_query = (const float*)d_in[1];
    const float* pc_w    = (const float*)d_in[2];
    const float* pc_b    = (const float*)d_in[3];
    const float* qc_w    = (const float*)d_in[4];
    const float* qc_b    = (const float*)d_in[5];
    const float* pm_w    = (const float*)d_in[6];
    const float* pm_b    = (const float*)d_in[7];
    const float* qm_w    = (const float*)d_in[8];
    const float* qm_b    = (const float*)d_in[9];
    float* out = (float*)d_out;
    float* ws  = (float*)d_ws;

    k_prepall<<<325, 1024, 0, stream>>>(x_query, qc_w, qc_b, pc_w, pc_b, pm_w, qm_w, ws);
    k_main<<<1024, 256, 0, stream>>>(x_props, x_query, pc_w, pc_b, pm_b, qm_b, ws,
                                     out + OUT_PA, out + OUT_FP, out + OUT_FQ);
}